// Round 1
// baseline (103.329 us; speedup 1.0000x reference)
//
#include <hip/hip_runtime.h>

#define BN_EPS 1e-5f
#define ALPHA 0.5f
#define BETA 0.5f

// B=32, C=1024, W=32, H=32, K=2
// Workspace layout (floats):
//   conv_w : [32][1024] at ws + 0
//   conv_h : [32][1024] at ws + 32768
//   fac    : [32][2][2] float2 (boost, mask) at ws + 65536

__global__ __launch_bounds__(256) void k_conv(
    const float* __restrict__ fm, const float* __restrict__ wW,
    const float* __restrict__ wH, float* __restrict__ conv_w,
    float* __restrict__ conv_h) {
  // grid = B * 16 ; each block: one batch, 64 channels, 1024 spatial positions
  const int blk = blockIdx.x;
  const int b = blk >> 4;
  const int cs = blk & 15;
  const int t = threadIdx.x;  // 0..255, owns spatial float4 at t
  const int c0 = cs * 64;
  const float4* f4 = reinterpret_cast<const float4*>(fm) +
                     ((size_t)b * 1024 + c0) * 256 + t;
  float4 aw = {0.f, 0.f, 0.f, 0.f};
  float4 ah = {0.f, 0.f, 0.f, 0.f};
#pragma unroll 4
  for (int cc = 0; cc < 64; ++cc) {
    const float4 v = f4[(size_t)cc * 256];
    const float sw = wW[c0 + cc];
    const float sh = wH[c0 + cc];
    aw.x = fmaf(v.x, sw, aw.x);
    aw.y = fmaf(v.y, sw, aw.y);
    aw.z = fmaf(v.z, sw, aw.z);
    aw.w = fmaf(v.w, sw, aw.w);
    ah.x = fmaf(v.x, sh, ah.x);
    ah.y = fmaf(v.y, sh, ah.y);
    ah.z = fmaf(v.z, sh, ah.z);
    ah.w = fmaf(v.w, sh, ah.w);
  }
  float* cw = conv_w + b * 1024 + t * 4;
  float* ch = conv_h + b * 1024 + t * 4;
  atomicAdd(cw + 0, aw.x);
  atomicAdd(cw + 1, aw.y);
  atomicAdd(cw + 2, aw.z);
  atomicAdd(cw + 3, aw.w);
  atomicAdd(ch + 0, ah.x);
  atomicAdd(ch + 1, ah.y);
  atomicAdd(ch + 2, ah.z);
  atomicAdd(ch + 3, ah.w);
}

__global__ __launch_bounds__(64) void k_factors(
    const float* __restrict__ conv_w, const float* __restrict__ conv_h,
    const float* __restrict__ bw, const float* __restrict__ gw,
    const float* __restrict__ betw, const float* __restrict__ mw,
    const float* __restrict__ vw, const float* __restrict__ bh,
    const float* __restrict__ gh, const float* __restrict__ beth,
    const float* __restrict__ mh, const float* __restrict__ vh,
    float2* __restrict__ fac) {
  const int b = blockIdx.x;  // one batch per block, 64 threads = 1 wave
  const int t = threadIdx.x;

  // BN folded to scale/shift; conv buffers hold raw sums (bias folded here)
  const float scale_w = gw[0] * rsqrtf(vw[0] + BN_EPS);
  const float shift_w = (bw[0] - mw[0]) * scale_w + betw[0];
  const float scale_h = gh[0] * rsqrtf(vh[0] + BN_EPS);
  const float shift_h = (bh[0] - mh[0]) * scale_h + beth[0];

  float s_w0 = 0.f, s_w1 = 0.f, s_h0 = 0.f, s_h1 = 0.f;
#pragma unroll
  for (int j = 0; j < 16; ++j) {
    const int e = t * 16 + j;  // e in [0,1024): w = e>>5, h = e&31
    const int w = e >> 5;
    const int h = e & 31;
    const float aw = fmaxf(fmaf(conv_w[b * 1024 + e], scale_w, shift_w), 0.f);
    const float ah = fmaxf(fmaf(conv_h[b * 1024 + e], scale_h, shift_h), 0.f);
    if (w < 16) s_w0 += aw; else s_w1 += aw;
    if (h < 16) s_h0 += ah; else s_h1 += ah;
  }
#pragma unroll
  for (int off = 32; off >= 1; off >>= 1) {
    s_w0 += __shfl_down(s_w0, off);
    s_w1 += __shfl_down(s_w1, off);
    s_h0 += __shfl_down(s_h0, off);
    s_h1 += __shfl_down(s_h1, off);
  }
  if (t == 0) {
    // strip means over 512 elements each
    const float pw0 = s_w0 * (1.f / 512.f), pw1 = s_w1 * (1.f / 512.f);
    const float ph0 = s_h0 * (1.f / 512.f), ph1 = s_h1 * (1.f / 512.f);
    // 2-way softmaxes
    const float mwv = fmaxf(pw0, pw1);
    const float ew0 = __expf(pw0 - mwv), ew1 = __expf(pw1 - mwv);
    const float sw0 = ew0 / (ew0 + ew1), sw1 = ew1 / (ew0 + ew1);
    const float mhv = fmaxf(ph0, ph1);
    const float eh0 = __expf(ph0 - mhv), eh1 = __expf(ph1 - mhv);
    const float sh0 = eh0 / (eh0 + eh1), sh1 = eh1 / (eh0 + eh1);

    float f[4];
    f[0] = sw0 * sh0;  // kw=0, kh=0
    f[1] = sw0 * sh1;  // kw=0, kh=1
    f[2] = sw1 * sh0;  // kw=1, kh=0
    f[3] = sw1 * sh1;  // kw=1, kh=1
    const float fmax4 =
        fmaxf(fmaxf(f[0], f[1]), fmaxf(f[2], f[3]));
    const float thr = fmax4 * 0.95f;
#pragma unroll
    for (int q = 0; q < 4; ++q) {
      const float boost = 1.f + ALPHA * f[q];
      const float mask = (f[q] < thr) ? 1.f : BETA;
      fac[b * 4 + q] = make_float2(boost, mask);
    }
  }
}

__global__ __launch_bounds__(256) void k_out(
    const float* __restrict__ fm, const float2* __restrict__ fac,
    float* __restrict__ out0, float* __restrict__ out1) {
  // one float4 per thread; 32Mi floats total -> 8Mi threads
  const size_t i = (size_t)blockIdx.x * 256 + threadIdx.x;  // float4 index
  const size_t e = i * 4;                                    // element index
  const int b = (int)(e >> 20);       // 1024*1024 elems per batch
  const int w = (int)(e >> 5) & 31;
  const int h = (int)e & 31;          // float4 stays within one h-quadrant
  const float2 f = fac[(b << 2) | ((w >> 4) << 1) | (h >> 4)];
  const float4 v = reinterpret_cast<const float4*>(fm)[i];
  float4 o0, o1;
  o0.x = v.x * f.x; o0.y = v.y * f.x; o0.z = v.z * f.x; o0.w = v.w * f.x;
  o1.x = v.x * f.y; o1.y = v.y * f.y; o1.z = v.z * f.y; o1.w = v.w * f.y;
  reinterpret_cast<float4*>(out0)[i] = o0;
  reinterpret_cast<float4*>(out1)[i] = o1;
}

extern "C" void kernel_launch(void* const* d_in, const int* in_sizes, int n_in,
                              void* d_out, int out_size, void* d_ws,
                              size_t ws_size, hipStream_t stream) {
  const float* fm = (const float*)d_in[0];
  const float* w_w = (const float*)d_in[1];
  const float* b_w = (const float*)d_in[2];
  const float* g_w = (const float*)d_in[3];
  const float* be_w = (const float*)d_in[4];
  const float* m_w = (const float*)d_in[5];
  const float* v_w = (const float*)d_in[6];
  const float* w_h = (const float*)d_in[7];
  const float* b_h = (const float*)d_in[8];
  const float* g_h = (const float*)d_in[9];
  const float* be_h = (const float*)d_in[10];
  const float* m_h = (const float*)d_in[11];
  const float* v_h = (const float*)d_in[12];

  float* ws = (float*)d_ws;
  float* conv_w = ws;                 // 32768 floats
  float* conv_h = ws + 32768;         // 32768 floats
  float2* fac = (float2*)(ws + 65536);  // 128 float2

  float* out0 = (float*)d_out;
  float* out1 = out0 + (size_t)32 * 1024 * 1024;  // 32Mi floats each

  // zero the conv accumulators (graph-capturable)
  hipMemsetAsync(d_ws, 0, 65536 * sizeof(float), stream);

  k_conv<<<32 * 16, 256, 0, stream>>>(fm, w_w, w_h, conv_w, conv_h);
  k_factors<<<32, 64, 0, stream>>>(conv_w, conv_h, b_w, g_w, be_w, m_w, v_w,
                                   b_h, g_h, be_h, m_h, v_h, fac);
  k_out<<<32768, 256, 0, stream>>>(fm, fac, out0, out1);
}

// Round 2
// 102.528 us; speedup vs baseline: 1.0078x; 1.0078x over previous
//
#include <hip/hip_runtime.h>

#define BN_EPS 1e-5f
#define ALPHA 0.5f
#define BETA 0.5f

// B=32, C=1024, W=32, H=32, K=2
// Workspace layout (floats):
//   pooled_w [32][2]           at ws + 0    (64 floats)
//   pooled_h [32][2]           at ws + 64   (64 floats)
//   fac      [32][4] (float2)  at ws + 128  (256 floats)

typedef float vfloat4 __attribute__((ext_vector_type(4)));

// One block = (batch b, w-row). Computes full channel reduction for 32
// spatial positions (one w row, all h), applies BN+ReLU, reduces to the
// strip-pooled partial sums with 3 global atomics.
__global__ __launch_bounds__(256) void k_conv(
    const float* __restrict__ fm, const float* __restrict__ wW,
    const float* __restrict__ wH, const float* __restrict__ bw,
    const float* __restrict__ gw, const float* __restrict__ betw,
    const float* __restrict__ mw, const float* __restrict__ vw,
    const float* __restrict__ bh, const float* __restrict__ gh,
    const float* __restrict__ beth, const float* __restrict__ mh,
    const float* __restrict__ vh, float* __restrict__ pooled_w,
    float* __restrict__ pooled_h) {
  __shared__ float lw[1024];
  __shared__ float lh[1024];
  __shared__ float4 part_w[32][8];
  __shared__ float4 part_h[32][8];

  const int t = threadIdx.x;
  const int b = blockIdx.x >> 5;    // batch
  const int row = blockIdx.x & 31;  // w row; 32 spatial positions = 8 float4

  // stage weights to LDS (coalesced float4 loads)
  {
    const float4 a = reinterpret_cast<const float4*>(wW)[t];
    const float4 c = reinterpret_cast<const float4*>(wH)[t];
    reinterpret_cast<float4*>(lw)[t] = a;
    reinterpret_cast<float4*>(lh)[t] = c;
  }
  __syncthreads();

  const int c_off = t >> 3;  // 0..31 channel group
  const int s4 = t & 7;      // 0..7 float4 within the row
  const float4* f4 = reinterpret_cast<const float4*>(fm) +
                     ((size_t)(b * 1024 + c_off) * 256 + row * 8 + s4);

  float4 aw = {0.f, 0.f, 0.f, 0.f};
  float4 ah = {0.f, 0.f, 0.f, 0.f};
#pragma unroll 8
  for (int it = 0; it < 32; ++it) {
    const int c = it * 32 + c_off;
    const float4 v = f4[(size_t)it * 32 * 256];
    const float sw = lw[c];
    const float sh = lh[c];
    aw.x = fmaf(v.x, sw, aw.x);
    aw.y = fmaf(v.y, sw, aw.y);
    aw.z = fmaf(v.z, sw, aw.z);
    aw.w = fmaf(v.w, sw, aw.w);
    ah.x = fmaf(v.x, sh, ah.x);
    ah.y = fmaf(v.y, sh, ah.y);
    ah.z = fmaf(v.z, sh, ah.z);
    ah.w = fmaf(v.w, sh, ah.w);
  }
  part_w[c_off][s4] = aw;
  part_h[c_off][s4] = ah;
  __syncthreads();

  if (t < 8) {
    const float scale_w = gw[0] * rsqrtf(vw[0] + BN_EPS);
    const float shift_w = (bw[0] - mw[0]) * scale_w + betw[0];
    const float scale_h = gh[0] * rsqrtf(vh[0] + BN_EPS);
    const float shift_h = (bh[0] - mh[0]) * scale_h + beth[0];

    float4 cw = {0.f, 0.f, 0.f, 0.f};
    float4 ch = {0.f, 0.f, 0.f, 0.f};
#pragma unroll
    for (int g = 0; g < 32; ++g) {
      const float4 pw = part_w[g][t];
      const float4 ph = part_h[g][t];
      cw.x += pw.x; cw.y += pw.y; cw.z += pw.z; cw.w += pw.w;
      ch.x += ph.x; ch.y += ph.y; ch.z += ph.z; ch.w += ph.w;
    }
    // BN + ReLU, then sum the 4 elements this lane owns
    float aws = fmaxf(fmaf(cw.x, scale_w, shift_w), 0.f) +
                fmaxf(fmaf(cw.y, scale_w, shift_w), 0.f) +
                fmaxf(fmaf(cw.z, scale_w, shift_w), 0.f) +
                fmaxf(fmaf(cw.w, scale_w, shift_w), 0.f);
    float ahs = fmaxf(fmaf(ch.x, scale_h, shift_h), 0.f) +
                fmaxf(fmaf(ch.y, scale_h, shift_h), 0.f) +
                fmaxf(fmaf(ch.z, scale_h, shift_h), 0.f) +
                fmaxf(fmaf(ch.w, scale_h, shift_h), 0.f);
    // lane t covers h = t*4..t*4+3 -> kh strip = (t>>2)&1
    const int kh = (t >> 2) & 1;
    float v0 = kh == 0 ? ahs : 0.f;
    float v1 = kh == 1 ? ahs : 0.f;
#pragma unroll
    for (int off = 4; off >= 1; off >>= 1) {
      aws += __shfl_xor(aws, off);
      v0 += __shfl_xor(v0, off);
      v1 += __shfl_xor(v1, off);
    }
    if (t == 0) {
      const int kw = row >> 4;
      atomicAdd(&pooled_w[b * 2 + kw], aws);
      atomicAdd(&pooled_h[b * 2 + 0], v0);
      atomicAdd(&pooled_h[b * 2 + 1], v1);
    }
  }
}

__global__ __launch_bounds__(64) void k_factors(
    const float* __restrict__ pooled_w, const float* __restrict__ pooled_h,
    float2* __restrict__ fac) {
  const int b = threadIdx.x;  // lanes 0..31 = batches
  if (b >= 32) return;
  const float pw0 = pooled_w[b * 2 + 0] * (1.f / 512.f);
  const float pw1 = pooled_w[b * 2 + 1] * (1.f / 512.f);
  const float ph0 = pooled_h[b * 2 + 0] * (1.f / 512.f);
  const float ph1 = pooled_h[b * 2 + 1] * (1.f / 512.f);

  const float mwv = fmaxf(pw0, pw1);
  const float ew0 = __expf(pw0 - mwv), ew1 = __expf(pw1 - mwv);
  const float sw0 = ew0 / (ew0 + ew1), sw1 = ew1 / (ew0 + ew1);
  const float mhv = fmaxf(ph0, ph1);
  const float eh0 = __expf(ph0 - mhv), eh1 = __expf(ph1 - mhv);
  const float sh0 = eh0 / (eh0 + eh1), sh1 = eh1 / (eh0 + eh1);

  float f[4];
  f[0] = sw0 * sh0;
  f[1] = sw0 * sh1;
  f[2] = sw1 * sh0;
  f[3] = sw1 * sh1;
  const float thr = fmaxf(fmaxf(f[0], f[1]), fmaxf(f[2], f[3])) * 0.95f;
#pragma unroll
  for (int q = 0; q < 4; ++q) {
    const float boost = 1.f + ALPHA * f[q];
    const float mask = (f[q] < thr) ? 1.f : BETA;
    fac[b * 4 + q] = make_float2(boost, mask);
  }
}

__global__ __launch_bounds__(256) void k_out(
    const float* __restrict__ fm, const float2* __restrict__ fac,
    float* __restrict__ out0, float* __restrict__ out1) {
  // 8,388,608 float4s total; 2,097,152 threads, 4 float4s each in
  // stride-2Mi chunks (each chunk's loads/stores perfectly coalesced).
  const size_t i0 = (size_t)blockIdx.x * 256 + threadIdx.x;
  const vfloat4* fm4 = reinterpret_cast<const vfloat4*>(fm);
  vfloat4* o0 = reinterpret_cast<vfloat4*>(out0);
  vfloat4* o1 = reinterpret_cast<vfloat4*>(out1);
#pragma unroll
  for (int k = 0; k < 4; ++k) {
    const size_t i = i0 + (size_t)k * 2097152;
    const size_t e = i * 4;
    const int b = (int)(e >> 20);
    const int kw = ((int)(e >> 5) & 31) >> 4;
    const int kh = ((int)e & 31) >> 4;
    const float2 f = fac[(b << 2) | (kw << 1) | kh];
    const vfloat4 v = fm4[i];
    __builtin_nontemporal_store(v * f.x, &o0[i]);
    __builtin_nontemporal_store(v * f.y, &o1[i]);
  }
}

extern "C" void kernel_launch(void* const* d_in, const int* in_sizes, int n_in,
                              void* d_out, int out_size, void* d_ws,
                              size_t ws_size, hipStream_t stream) {
  const float* fm = (const float*)d_in[0];
  const float* w_w = (const float*)d_in[1];
  const float* b_w = (const float*)d_in[2];
  const float* g_w = (const float*)d_in[3];
  const float* be_w = (const float*)d_in[4];
  const float* m_w = (const float*)d_in[5];
  const float* v_w = (const float*)d_in[6];
  const float* w_h = (const float*)d_in[7];
  const float* b_h = (const float*)d_in[8];
  const float* g_h = (const float*)d_in[9];
  const float* be_h = (const float*)d_in[10];
  const float* m_h = (const float*)d_in[11];
  const float* v_h = (const float*)d_in[12];

  float* ws = (float*)d_ws;
  float* pooled_w = ws;                  // 64 floats
  float* pooled_h = ws + 64;             // 64 floats
  float2* fac = (float2*)(ws + 128);     // 128 float2

  float* out0 = (float*)d_out;
  float* out1 = out0 + (size_t)32 * 1024 * 1024;

  hipMemsetAsync(d_ws, 0, 128 * sizeof(float), stream);

  k_conv<<<32 * 32, 256, 0, stream>>>(fm, w_w, w_h, b_w, g_w, be_w, m_w, v_w,
                                      b_h, g_h, be_h, m_h, v_h, pooled_w,
                                      pooled_h);
  k_factors<<<1, 64, 0, stream>>>(pooled_w, pooled_h, fac);
  k_out<<<8192, 256, 0, stream>>>(fm, fac, out0, out1);
}